// Round 5
// baseline (320.810 us; speedup 1.0000x reference)
//
#include <hip/hip_runtime.h>

// EmbeddingCRF: feats = emb[sentence] @ W^T; CRF forward (LSE), gold score,
// Viterbi decode. Parallel-in-time via 12x12 semiring transfer matrices.
// R5: node-count reduction 9 -> 4 (launch gap ~8us/node dominates controllable
// time). k_chunk = feats+matrices fused; k_top = fold2+mid+expandA+gold;
// k_bottom = expandB+decode fused. EXPF/FMAX/BV/SFX live only in LDS now.

#define LSEQ    32768
#define NTAGS   14
#define R       12
#define T_START 12
#define T_STOP  13
#define EMBD    300
#define CCH     2048  // chunks of 16 steps
#define SCH     16
#define NSUP    128   // supers (16 chunks)
#define NHYP    8     // hypers (16 supers)

// ws layout (float offsets)
#define OFF_FEATS 0         // [32768][12]
#define OFF_PF    393216    // [2048][144] LSE chunk mats (log domain)
#define OFF_PV    688128    // [2048][144] max-plus chunk mats
#define OFF_PVC   983040    // [2048][144] transposed
#define OFF_SMV   1277952   // [128][144]
#define OFF_SMVT  1296384   // [128][144]
#define OFF_SMF   1314816   // [128][144]
#define OFF_SBV   1333248   // [128][12]
#define OFF_SSFX  1334784   // [128][12]
#define OFF_GOLDP 1336320   // [2048] per-chunk gold partials

__device__ __forceinline__ void load12(const float* __restrict__ p, float* r) {
  const float4* p4 = (const float4*)p;
  float4 a = p4[0], b = p4[1], c = p4[2];
  r[0]=a.x; r[1]=a.y; r[2]=a.z; r[3]=a.w;
  r[4]=b.x; r[5]=b.y; r[6]=b.z; r[7]=b.w;
  r[8]=c.x; r[9]=c.y; r[10]=c.z; r[11]=c.w;
}

__device__ __forceinline__ void lds12(const float* p, float* r) {
  const float4* p4 = (const float4*)p;
  float4 a = p4[0], b = p4[1], c = p4[2];
  r[0]=a.x; r[1]=a.y; r[2]=a.z; r[3]=a.w;
  r[4]=b.x; r[5]=b.y; r[6]=b.z; r[7]=b.w;
  r[8]=c.x; r[9]=c.y; r[10]=c.z; r[11]=c.w;
}

// ---------------- K1: fused feats + chunk transfer matrices + gold ----------
// 2048 blocks x 128. Phase 1: 16 positions' feats into LDS (+FEATS global,
// +gold partial). Phase 2: wave0 = viterbi matrix, wave1 = exp-domain LSE.
__global__ __launch_bounds__(128) void k_chunk(
    const int* __restrict__ sentence, const int* __restrict__ tags,
    const float* __restrict__ emb, const float* __restrict__ W,
    const float* __restrict__ trans, float* __restrict__ ws)
{
  __shared__ __align__(16) float Wl[R * EMBD];
  __shared__ __align__(16) float fl[SCH][12];
  __shared__ __align__(16) float efl[SCH][12];
  __shared__ float fml[SCH];
  __shared__ float gsh;
  int tid = threadIdx.x;
  int bid = blockIdx.x;
  for (int i = tid; i < R * EMBD; i += 128) Wl[i] = W[i];
  if (tid == 0) gsh = 0.f;
  __syncthreads();

  int grp = tid >> 4;           // 0..7
  int g   = tid & 15;
  #pragma unroll
  for (int r = 0; r < 2; ++r) {
    int loc = r * 8 + grp;      // 0..15
    int pos = bid * SCH + loc;
    int row = sentence[pos];
    float acc = 0.f;
    if (g < R) {
      const float4* e4 = (const float4*)(emb + (size_t)row * EMBD);
      const float4* w4 = (const float4*)(Wl + g * EMBD);
      #pragma unroll 5
      for (int i = 0; i < EMBD / 4; ++i) {
        float4 a = e4[i]; float4 b = w4[i];
        acc += a.x*b.x + a.y*b.y + a.z*b.z + a.w*b.w;
      }
    }
    float feat = (g < R) ? acc : -3.0e38f;
    float mx = feat;
    #pragma unroll
    for (int off = 1; off < 16; off <<= 1)
      mx = fmaxf(mx, __shfl_xor(mx, off, 16));
    if (g < R) {
      ws[OFF_FEATS + pos * 12 + g] = feat;
      fl[loc][g]  = feat;
      efl[loc][g] = __expf(feat - mx);
    }
    if (g == 0) fml[loc] = mx;
    int tg = tags[pos];
    if (g == tg) {
      int prev = (pos == 0) ? T_START : tags[pos - 1];
      float gc = feat + trans[tg * NTAGS + prev];
      if (pos == LSEQ - 1) gc += trans[T_STOP * NTAGS + tg];
      atomicAdd(&gsh, gc);
    }
  }
  __syncthreads();
  if (tid == 0) ws[OFF_GOLDP + bid] = gsh;

  int wid = tid >> 6;
  int p = tid & 15;
  int t0 = (bid == 0) ? 1 : 0;
  if ((tid & 63) < 16) {
    if (wid == 0) {
      // viterbi chunk matrix, column p
      float Treg[R][R];
      #pragma unroll
      for (int n = 0; n < R; ++n)
        #pragma unroll
        for (int m = 0; m < R; ++m)
          Treg[n][m] = trans[n * NTAGS + m];
      float V[R];
      #pragma unroll
      for (int m = 0; m < R; ++m) V[m] = (m == p) ? 0.f : -1.0e30f;
      for (int t = t0; t < SCH; ++t) {
        float NV[R];
        #pragma unroll
        for (int n = 0; n < R; ++n) {
          float b = Treg[n][0] + V[0];
          #pragma unroll
          for (int m = 1; m < R; ++m) b = fmaxf(b, Treg[n][m] + V[m]);
          NV[n] = b + fl[t][n];
        }
        #pragma unroll
        for (int n = 0; n < R; ++n) V[n] = NV[n];
      }
      if (p < R) {
        #pragma unroll
        for (int n = 0; n < R; ++n) {
          ws[OFF_PV  + bid * 144 + n * 12 + p] = V[n];
          ws[OFF_PVC + bid * 144 + p * 12 + n] = V[n];
        }
      }
    } else {
      // LSE chunk matrix, exp domain w/ pow2 rescale
      float Treg[R][R];
      #pragma unroll
      for (int n = 0; n < R; ++n)
        #pragma unroll
        for (int m = 0; m < R; ++m)
          Treg[n][m] = __expf(trans[n * NTAGS + m]);
      float E[R];
      #pragma unroll
      for (int m = 0; m < R; ++m) E[m] = (m == p) ? 1.f : 0.f;
      int kacc = 0;
      float sfeat = 0.f;
      for (int t = t0; t < SCH; ++t) {
        sfeat += fml[t];
        float NE[R];
        #pragma unroll
        for (int n = 0; n < R; ++n) {
          float s = Treg[n][0] * E[0];
          #pragma unroll
          for (int m = 1; m < R; ++m) s = fmaf(Treg[n][m], E[m], s);
          NE[n] = s * efl[t][n];
        }
        #pragma unroll
        for (int n = 0; n < R; ++n) E[n] = NE[n];
        if ((t & 7) == 7) {
          float mx = E[0];
          #pragma unroll
          for (int n = 1; n < R; ++n) mx = fmaxf(mx, E[n]);
          if (mx > 0.f) {
            int k = ((__float_as_int(mx) >> 23) & 0xFF) - 127;
            float sc = __int_as_float((127 - k) << 23);
            #pragma unroll
            for (int n = 0; n < R; ++n) E[n] *= sc;
            kacc += k;
          }
        }
      }
      if (p < R) {
        float base = (float)kacc * 0.6931471805599453f + sfeat;
        #pragma unroll
        for (int n = 0; n < R; ++n)
          ws[OFF_PF + bid * 144 + n * 12 + p] =
              (E[n] > 0.f) ? (__logf(E[n]) + base) : -1.0e30f;
      }
    }
  }
}

// ---------------- K2: fold chunks -> supers (elem-parallel) ----------------
// 256 blocks x 192; blockIdx&1: 0 = viterbi, 1 = LSE.
__global__ __launch_bounds__(192) void k_fold1(
    float* __restrict__ ws)
{
  __shared__ __align__(16) float Ml[144];
  __shared__ __align__(16) float Vl[144];
  int s   = blockIdx.x >> 1;
  int sem = blockIdx.x & 1;
  int l = threadIdx.x;
  bool act = (l < 144);
  int n = l / 12;
  int p = l - n * 12;
  int base = sem ? OFF_PF : OFF_PV;

  float V = (act && n == p) ? 0.f : -1.0e30f;
  float mreg = act ? ws[base + (s * 16) * 144 + l] : 0.f;

  for (int j = 0; j < 16; ++j) {
    if (act) { Ml[l] = mreg; Vl[l] = V; }
    __syncthreads();
    if (act) mreg = ws[base + (s * 16 + j + 1) * 144 + l];  // off-end: adjacent region, safe
    if (act) {
      if (sem == 0) {
        float best = -3.0e38f;
        #pragma unroll
        for (int m = 0; m < R; ++m)
          best = fmaxf(best, Ml[n * 12 + m] + Vl[m * 12 + p]);
        V = best;
      } else {
        float cand[R]; float mx = -3.0e38f;
        #pragma unroll
        for (int m = 0; m < R; ++m) {
          cand[m] = Ml[n * 12 + m] + Vl[m * 12 + p];
          mx = fmaxf(mx, cand[m]);
        }
        float sum = 0.f;
        #pragma unroll
        for (int m = 0; m < R; ++m) sum += __expf(cand[m] - mx);
        V = mx + __logf(sum);
      }
    }
    __syncthreads();
  }
  if (act) {
    if (sem == 0) {
      ws[OFF_SMV  + s * 144 + n * 12 + p] = V;
      ws[OFF_SMVT + s * 144 + p * 12 + n] = V;
    } else {
      ws[OFF_SMF + s * 144 + n * 12 + p] = V;
    }
  }
}

// ---------------- K3: single-block top — fold2 + mid + expandA + gold -------
__global__ __launch_bounds__(256) void k_top(
    const float* __restrict__ trans, float* __restrict__ ws,
    float* __restrict__ out)
{
  __shared__ __align__(16) float HMV [NHYP][144];
  __shared__ __align__(16) float HMVT[NHYP][144];
  __shared__ __align__(16) float HMF [NHYP][144];
  __shared__ __align__(16) float HBV [NHYP][12];
  __shared__ __align__(16) float HSFX[NHYP][12];
  __shared__ __align__(16) float Vsh[3][16];
  __shared__ __align__(16) float Vex[16][16];
  __shared__ float gsh;
  int tid = threadIdx.x;
  if (tid == 0) gsh = 0.f;
  __syncthreads();

  // phase 0: gold sum (wave-reduced)
  {
    float gs = 0.f;
    for (int i = tid; i < CCH; i += 256) gs += ws[OFF_GOLDP + i];
    #pragma unroll
    for (int off = 32; off >= 1; off >>= 1) gs += __shfl_xor(gs, off, 64);
    if ((tid & 63) == 0) atomicAdd(&gsh, gs);
  }

  // phase 1: column-parallel 16-way folds: supers -> hypers (in LDS)
  {
    int gI = tid >> 4;      // task 0..15
    int p  = tid & 15;
    float V[R];
    #pragma unroll
    for (int m = 0; m < R; ++m) V[m] = (m == p) ? 0.f : -1.0e30f;
    if (gI < 8) {           // viterbi tasks: waves 0-1
      int h = gI;
      for (int j = 0; j < 16; ++j) {
        const float* M = ws + OFF_SMV + (h * 16 + j) * 144;
        float row[R], rown[R];
        load12(M, row);
        float NV[R];
        #pragma unroll
        for (int n = 0; n < R; ++n) {
          if (n < 11) load12(M + (n + 1) * 12, rown);
          float b = row[0] + V[0];
          #pragma unroll
          for (int m = 1; m < R; ++m) b = fmaxf(b, row[m] + V[m]);
          NV[n] = b;
          #pragma unroll
          for (int m = 0; m < R; ++m) row[m] = rown[m];
        }
        #pragma unroll
        for (int n = 0; n < R; ++n) V[n] = NV[n];
      }
      if (p < R) {
        #pragma unroll
        for (int n = 0; n < R; ++n) {
          HMV [h][n * 12 + p] = V[n];
          HMVT[h][p * 12 + n] = V[n];
        }
      }
    } else {                // LSE tasks: waves 2-3
      int h = gI - 8;
      for (int j = 0; j < 16; ++j) {
        const float* M = ws + OFF_SMF + (h * 16 + j) * 144;
        float row[R], rown[R];
        load12(M, row);
        float NV[R];
        #pragma unroll
        for (int n = 0; n < R; ++n) {
          if (n < 11) load12(M + (n + 1) * 12, rown);
          float tv[R]; float mx = -3.0e38f;
          #pragma unroll
          for (int m = 0; m < R; ++m) { tv[m] = row[m] + V[m]; mx = fmaxf(mx, tv[m]); }
          float sum = 0.f;
          #pragma unroll
          for (int m = 0; m < R; ++m) sum += __expf(tv[m] - mx);
          NV[n] = mx + __logf(sum);
          #pragma unroll
          for (int m = 0; m < R; ++m) row[m] = rown[m];
        }
        #pragma unroll
        for (int n = 0; n < R; ++n) V[n] = NV[n];
      }
      if (p < R) {
        #pragma unroll
        for (int n = 0; n < R; ++n) HMF[h][n * 12 + p] = V[n];
      }
    }
  }
  __syncthreads();

  // phase 2: 8-step mid scans on three separate waves
  {
    int wv = tid >> 6;
    int lane = tid & 63;
    int n = lane;
    bool act = (n < R);
    if (wv == 0 && lane < 16) {
      float v = -3.0e38f;
      if (act) { v = trans[n * NTAGS + T_START] + ws[OFF_FEATS + n]; HBV[0][n] = v; }
      Vsh[0][lane] = v;
      float row[R], rown[R];
      if (act) lds12(&HMV[0][n * 12], row);
      for (int h = 0; h < NHYP; ++h) {
        if (act && h < NHYP - 1) lds12(&HMV[h + 1][n * 12], rown);
        float vv[R]; lds12(Vsh[0], vv);
        if (act) {
          float nx = row[0] + vv[0];
          #pragma unroll
          for (int m = 1; m < R; ++m) nx = fmaxf(nx, row[m] + vv[m]);
          if (h < NHYP - 1) HBV[h + 1][n] = nx;
          Vsh[0][n] = nx;
          #pragma unroll
          for (int m = 0; m < R; ++m) row[m] = rown[m];
        }
      }
      if (lane == 0) {
        float vv[R]; lds12(Vsh[0], vv);
        float ps = -3.0e38f;
        #pragma unroll
        for (int m = 0; m < R; ++m) ps = fmaxf(ps, vv[m] + trans[T_STOP * NTAGS + m]);
        out[1] = ps;
      }
    } else if (wv == 1 && lane < 16) {
      float v = -3.0e38f;
      if (act) { v = trans[T_STOP * NTAGS + n]; HSFX[NHYP - 1][n] = v; }
      Vsh[1][lane] = v;
      float row[R], rown[R];
      if (act) lds12(&HMVT[NHYP - 1][n * 12], row);
      for (int h = NHYP - 1; h >= 1; --h) {
        if (act && h > 1) lds12(&HMVT[h - 1][n * 12], rown);
        float vv[R]; lds12(Vsh[1], vv);
        if (act) {
          float nx = row[0] + vv[0];
          #pragma unroll
          for (int m = 1; m < R; ++m) nx = fmaxf(nx, row[m] + vv[m]);
          HSFX[h - 1][n] = nx;
          Vsh[1][n] = nx;
          #pragma unroll
          for (int m = 0; m < R; ++m) row[m] = rown[m];
        }
      }
    } else if (wv == 2 && lane < 16) {
      float v = -3.0e38f;
      if (act) v = trans[n * NTAGS + T_START] + ws[OFF_FEATS + n];
      Vsh[2][lane] = v;
      float row[R], rown[R];
      if (act) lds12(&HMF[0][n * 12], row);
      for (int h = 0; h < NHYP; ++h) {
        if (act && h < NHYP - 1) lds12(&HMF[h + 1][n * 12], rown);
        float vv[R]; lds12(Vsh[2], vv);
        if (act) {
          float tv[R]; float mx = -3.0e38f;
          #pragma unroll
          for (int m = 0; m < R; ++m) { tv[m] = row[m] + vv[m]; mx = fmaxf(mx, tv[m]); }
          float sum = 0.f;
          #pragma unroll
          for (int m = 0; m < R; ++m) sum += __expf(tv[m] - mx);
          Vsh[2][n] = mx + __logf(sum);
          #pragma unroll
          for (int m = 0; m < R; ++m) row[m] = rown[m];
        }
      }
      if (lane == 0) {
        float vv[R]; lds12(Vsh[2], vv);
        float mx = -3.0e38f;
        #pragma unroll
        for (int m = 0; m < R; ++m) mx = fmaxf(mx, vv[m] + trans[T_STOP * NTAGS + m]);
        float sum = 0.f;
        #pragma unroll
        for (int m = 0; m < R; ++m) sum += __expf(vv[m] + trans[T_STOP * NTAGS + m] - mx);
        out[0] = (mx + __logf(sum)) - gsh;
      }
    }
  }
  __syncthreads();

  // phase 3: expandA — hyper vectors -> super vectors (branchless dirs)
  {
    int t16 = tid >> 4;         // task 0..15
    int h = t16 >> 1, dir = t16 & 1;
    int nn = tid & 15;
    bool a2 = (nn < R);
    const float* mb = ws + (dir ? OFF_SMVT : OFF_SMV);
    int obase = dir ? OFF_SSFX : OFF_SBV;
    float v = -3.0e38f;
    if (a2) v = dir ? HSFX[h][nn] : HBV[h][nn];
    Vex[t16][nn] = v;
    int s0 = dir ? (h * 16 + 15) : (h * 16);
    if (a2) ws[obase + s0 * 12 + nn] = v;
    float row[R], rown[R];
    if (a2) load12(mb + s0 * 144 + nn * 12, row);
    for (int j = 0; j < 15; ++j) {
      int mi   = dir ? (h * 16 + 15 - j) : (h * 16 + j);
      int minx = dir ? (mi - 1) : (mi + 1);
      if (a2) load12(mb + minx * 144 + nn * 12, rown);
      float vv[R]; lds12(Vex[t16], vv);
      if (a2) {
        float nx = row[0] + vv[0];
        #pragma unroll
        for (int m = 1; m < R; ++m) nx = fmaxf(nx, row[m] + vv[m]);
        ws[obase + minx * 12 + nn] = nx;
        Vex[t16][nn] = nx;
        #pragma unroll
        for (int m = 0; m < R; ++m) row[m] = rown[m];
      }
    }
  }
}

// ---------------- K4: fused expandB + decode, one block per super ----------
__global__ __launch_bounds__(256) void k_bottom(
    const float* __restrict__ trans, const float* __restrict__ ws,
    float* __restrict__ out)
{
  __shared__ __align__(16) float bvl [16][16];
  __shared__ __align__(16) float sfxl[16][16];
  __shared__ __align__(16) float Vsh2[16][16];
  __shared__ unsigned char bp[16][SCH][16];
  int tid = threadIdx.x;
  int s = blockIdx.x;

  // phase A: fwd chain (threads 0-15, wave 0) and bwd chain (64-79, wave 1)
  if (tid < 16) {
    int n = tid;
    bool act = (n < R);
    float v = act ? ws[OFF_SBV + s * 12 + n] : -1.0e30f;
    if (act) bvl[0][n] = v;
    Vsh2[0][n] = v;
    float row[R], rown[R];
    if (act) load12(ws + OFF_PV + (s * 16) * 144 + n * 12, row);
    for (int j = 0; j < 15; ++j) {
      if (act) load12(ws + OFF_PV + (s * 16 + j + 1) * 144 + n * 12, rown);
      float vv[R]; lds12(Vsh2[0], vv);
      if (act) {
        float nx = row[0] + vv[0];
        #pragma unroll
        for (int m = 1; m < R; ++m) nx = fmaxf(nx, row[m] + vv[m]);
        bvl[j + 1][n] = nx;
        Vsh2[0][n] = nx;
        #pragma unroll
        for (int m = 0; m < R; ++m) row[m] = rown[m];
      }
    }
  } else if (tid >= 64 && tid < 80) {
    int n = tid - 64;
    bool act = (n < R);
    float v = act ? ws[OFF_SSFX + s * 12 + n] : -1.0e30f;
    if (act) sfxl[15][n] = v;
    Vsh2[1][n] = v;
    float row[R], rown[R];
    if (act) load12(ws + OFF_PVC + (s * 16 + 15) * 144 + n * 12, row);
    for (int j = 15; j >= 1; --j) {
      if (act) load12(ws + OFF_PVC + (s * 16 + j - 1) * 144 + n * 12, rown);
      float vv[R]; lds12(Vsh2[1], vv);
      if (act) {
        float nx = row[0] + vv[0];
        #pragma unroll
        for (int m = 1; m < R; ++m) nx = fmaxf(nx, row[m] + vv[m]);
        sfxl[j - 1][n] = nx;
        Vsh2[1][n] = nx;
        #pragma unroll
        for (int m = 0; m < R; ++m) row[m] = rown[m];
      }
    }
  }
  __syncthreads();

  // phase B: decode 16 chunks in parallel (group j = chunk s*16+j)
  int j = tid >> 4;
  int g = tid & 15;
  int c = s * 16 + j;
  int t0 = (c == 0) ? 1 : c * SCH;
  int t1 = c * SCH + SCH;
  bool act = (g < R);

  float treg[R];
  #pragma unroll
  for (int m = 0; m < R; ++m) treg[m] = act ? trans[g * NTAGS + m] : 0.f;

  float fv = act ? bvl[j][g] : -3.0e38f;
  Vsh2[j][g] = fv;
  float fc = ws[OFF_FEATS + t0 * 12 + g];

  for (int t = t0; t < t1; ++t) {
    float fn = ws[OFF_FEATS + (t + 1) * 12 + g];   // off-end: PF region, unused
    float v[R];
    lds12(Vsh2[j], v);
    float best = -3.0e38f; int bi = 0;
    #pragma unroll
    for (int m = 0; m < R; ++m) {
      float cand = treg[m] + v[m];
      if (cand > best) { best = cand; bi = m; }
    }
    float nfv = best + fc;
    if (act) {
      bp[j][t - t0][g] = (unsigned char)bi;
      Vsh2[j][g] = nfv;
    }
    fc = fn;
  }

  Vsh2[j][g] = act ? (Vsh2[j][g] + sfxl[j][g]) : -3.0e38f;

  if (g == 0) {
    float best = Vsh2[j][0]; int idx = 0;
    #pragma unroll
    for (int m = 1; m < R; ++m) {
      float v = Vsh2[j][m];
      if (v > best) { best = v; idx = m; }
    }
    int cur = idx;
    int len = t1 - t0;
    out[2 + t0 + len - 1] = (float)cur;
    for (int tt = len - 1; tt >= 1; --tt) {
      cur = bp[j][tt][cur];
      out[2 + t0 + tt - 1] = (float)cur;
    }
    if (c == 0) {
      cur = bp[j][0][cur];
      out[2 + 0] = (float)cur;
    }
  }
}

extern "C" void kernel_launch(void* const* d_in, const int* in_sizes, int n_in,
                              void* d_out, int out_size, void* d_ws, size_t ws_size,
                              hipStream_t stream) {
  (void)in_sizes; (void)n_in; (void)out_size; (void)ws_size;
  const int*   sentence = (const int*)d_in[0];
  const int*   tags     = (const int*)d_in[1];
  const float* emb      = (const float*)d_in[2];
  const float* W        = (const float*)d_in[3];
  const float* trans    = (const float*)d_in[4];
  float* ws  = (float*)d_ws;
  float* out = (float*)d_out;

  k_chunk<<<CCH, 128, 0, stream>>>(sentence, tags, emb, W, trans, ws);
  k_fold1<<<NSUP * 2, 192, 0, stream>>>(ws);
  k_top<<<1, 256, 0, stream>>>(trans, ws, out);
  k_bottom<<<NSUP, 256, 0, stream>>>(trans, ws, out);
}